// Round 1
// baseline (2328.328 us; speedup 1.0000x reference)
//
#include <hip/hip_runtime.h>
#include <math.h>

#define NN 75000
#define NE 150000
#define H 44
#define HH 1936          // H*H
#define EDIM 10
#define NFRAG 15000
#define NGRAPH 1500

typedef const float* __restrict__ cfp;
typedef float* __restrict__ fpt;
typedef const int* __restrict__ cip;

__device__ __forceinline__ float relu_(float v){ return v > 0.f ? v : 0.f; }
__device__ __forceinline__ float sigmoid_(float v){ return 1.f/(1.f + expf(-v)); }

// out = relu(x @ W0 + b0)   (N x H)
__global__ __launch_bounds__(256) void k_in(cfp x, cfp W0, cfp b0, fpt out){
    __shared__ float sW[HH];
    __shared__ float sb[H];
    for(int i=threadIdx.x;i<HH;i+=256) sW[i]=W0[i];
    if(threadIdx.x<H) sb[threadIdx.x]=b0[threadIdx.x];
    __syncthreads();
    int n = blockIdx.x*256 + threadIdx.x;
    if(n>=NN) return;
    float acc[H];
    #pragma unroll
    for(int o=0;o<H;o++) acc[o]=sb[o];
    for(int h=0;h<H;h++){
        float xh = x[(size_t)n*H + h];
        const float4* wr = (const float4*)(sW + h*H);
        #pragma unroll
        for(int o=0;o<11;o++){
            float4 w = wr[o];
            acc[4*o]+=xh*w.x; acc[4*o+1]+=xh*w.y; acc[4*o+2]+=xh*w.z; acc[4*o+3]+=xh*w.w;
        }
    }
    float4* op = (float4*)(out + (size_t)n*H);
    #pragma unroll
    for(int i=0;i<11;i++) op[i] = make_float4(relu_(acc[4*i]),relu_(acc[4*i+1]),relu_(acc[4*i+2]),relu_(acc[4*i+3]));
}

// b2[n,o] = sum_h out[n,h] * be2[h*H+o]   (be2 viewed as H x H)
__global__ __launch_bounds__(256) void k_b2(cfp out, cfp be2, fpt b2){
    __shared__ float sB[HH];
    for(int i=threadIdx.x;i<HH;i+=256) sB[i]=be2[i];
    __syncthreads();
    int n = blockIdx.x*256 + threadIdx.x;
    if(n>=NN) return;
    float acc[H];
    #pragma unroll
    for(int o=0;o<H;o++) acc[o]=0.f;
    for(int h=0;h<H;h++){
        float oh = out[(size_t)n*H + h];
        const float4* wr = (const float4*)(sB + h*H);
        #pragma unroll
        for(int o=0;o<11;o++){
            float4 w = wr[o];
            acc[4*o]+=oh*w.x; acc[4*o+1]+=oh*w.y; acc[4*o+2]+=oh*w.z; acc[4*o+3]+=oh*w.w;
        }
    }
    float4* bp = (float4*)(b2 + (size_t)n*H);
    #pragma unroll
    for(int i=0;i<11;i++) bp[i] = make_float4(acc[4*i],acc[4*i+1],acc[4*i+2],acc[4*i+3]);
}

// t = relu(edge_attr @ We1 + be1)   (E x ED)
__global__ __launch_bounds__(256) void k_edge(cfp ea, cfp We1, cfp be1, fpt t){
    __shared__ float sW[EDIM*EDIM];
    __shared__ float sb[EDIM];
    if(threadIdx.x<EDIM*EDIM) sW[threadIdx.x]=We1[threadIdx.x];
    if(threadIdx.x<EDIM) sb[threadIdx.x]=be1[threadIdx.x];
    __syncthreads();
    int e = blockIdx.x*256 + threadIdx.x;
    if(e>=NE) return;
    float acc[EDIM];
    #pragma unroll
    for(int j=0;j<EDIM;j++) acc[j]=sb[j];
    for(int k=0;k<EDIM;k++){
        float a = ea[(size_t)e*EDIM + k];
        #pragma unroll
        for(int j=0;j<EDIM;j++) acc[j]+=a*sW[k*EDIM+j];
    }
    #pragma unroll
    for(int j=0;j<EDIM;j++) t[(size_t)e*EDIM+j]=relu_(acc[j]);
}

// msg[e,o] = sum_k sum_h t[e,k]*out[src,h]*We2[k,h*H+o] + b2[src,o]; atomic scatter to agg[dst]
__global__ __launch_bounds__(256,2) void k_msg(cfp out, cfp b2, cfp t, cfp We2, cip ei, fpt agg){
    __shared__ float4 sW[EDIM*HH/4];   // 4840 float4 = 77440 B
    const float4* wg = (const float4*)We2;
    for(int i=threadIdx.x;i<EDIM*HH/4;i+=256) sW[i]=wg[i];
    __syncthreads();
    int e = blockIdx.x*256 + threadIdx.x;
    if(e>=NE) return;
    int s = ei[e], d = ei[NE + e];
    float ov[H];
    const float4* op = (const float4*)(out + (size_t)s*H);
    #pragma unroll
    for(int i=0;i<11;i++){ float4 v=op[i]; ov[4*i]=v.x; ov[4*i+1]=v.y; ov[4*i+2]=v.z; ov[4*i+3]=v.w; }
    float4 msg[11];
    const float4* bp = (const float4*)(b2 + (size_t)s*H);
    #pragma unroll
    for(int i=0;i<11;i++) msg[i]=bp[i];
    for(int k=0;k<EDIM;k++){
        float tk = t[(size_t)e*EDIM + k];
        const float4* wrow = &sW[k*(HH/4)];
        #pragma unroll
        for(int h=0;h<H;h++){
            float z = tk*ov[h];
            #pragma unroll
            for(int o=0;o<11;o++){
                float4 w = wrow[h*11+o];
                msg[o].x+=z*w.x; msg[o].y+=z*w.y; msg[o].z+=z*w.z; msg[o].w+=z*w.w;
            }
        }
    }
    float* ag = agg + (size_t)d*H;
    #pragma unroll
    for(int o=0;o<11;o++){
        atomicAdd(ag+4*o  , msg[o].x);
        atomicAdd(ag+4*o+1, msg[o].y);
        atomicAdd(ag+4*o+2, msg[o].z);
        atomicAdd(ag+4*o+3, msg[o].w);
    }
}

// m = relu(agg + out@root + conv_b); out_nxt = [m, out] @ Wm + bm. agg reused as scratch for m.
__global__ __launch_bounds__(256) void k_comb(cfp out, fpt agg, cfp root, cfp conv_b, cfp Wm, cfp bm, fpt out_nxt){
    __shared__ float sR[HH];
    __shared__ float sM[2*HH];
    __shared__ float scb[H];
    __shared__ float sbm[H];
    for(int i=threadIdx.x;i<HH;i+=256) sR[i]=root[i];
    for(int i=threadIdx.x;i<2*HH;i+=256) sM[i]=Wm[i];
    if(threadIdx.x<H){ scb[threadIdx.x]=conv_b[threadIdx.x]; sbm[threadIdx.x]=bm[threadIdx.x]; }
    __syncthreads();
    int n = blockIdx.x*256 + threadIdx.x;
    if(n>=NN) return;
    float m[H];
    const float4* ap = (const float4*)(agg + (size_t)n*H);
    #pragma unroll
    for(int i=0;i<11;i++){
        float4 v=ap[i];
        m[4*i]=v.x+scb[4*i]; m[4*i+1]=v.y+scb[4*i+1]; m[4*i+2]=v.z+scb[4*i+2]; m[4*i+3]=v.w+scb[4*i+3];
    }
    for(int h=0;h<H;h++){
        float oh = out[(size_t)n*H + h];
        const float4* wr = (const float4*)(sR + h*H);
        #pragma unroll
        for(int o=0;o<11;o++){
            float4 w=wr[o];
            m[4*o]+=oh*w.x; m[4*o+1]+=oh*w.y; m[4*o+2]+=oh*w.z; m[4*o+3]+=oh*w.w;
        }
    }
    #pragma unroll
    for(int o=0;o<H;o++) m[o]=relu_(m[o]);
    float4* aw = (float4*)(agg + (size_t)n*H);
    #pragma unroll
    for(int i=0;i<11;i++) aw[i]=make_float4(m[4*i],m[4*i+1],m[4*i+2],m[4*i+3]);
    float no[H];
    #pragma unroll
    for(int o=0;o<H;o++) no[o]=sbm[o];
    for(int h=0;h<H;h++){
        float mh = agg[(size_t)n*H + h];   // reload own row (compile-time-safe rolled index)
        float oh = out[(size_t)n*H + h];
        const float4* w1 = (const float4*)(sM + h*H);
        const float4* w2 = (const float4*)(sM + (H+h)*H);
        #pragma unroll
        for(int o=0;o<11;o++){
            float4 a=w1[o], b=w2[o];
            no[4*o]+=mh*a.x+oh*b.x; no[4*o+1]+=mh*a.y+oh*b.y; no[4*o+2]+=mh*a.z+oh*b.z; no[4*o+3]+=mh*a.w+oh*b.w;
        }
    }
    float4* np_ = (float4*)(out_nxt + (size_t)n*H);
    #pragma unroll
    for(int i=0;i<11;i++) np_[i]=make_float4(no[4*i],no[4*i+1],no[4*i+2],no[4*i+3]);
}

// nodef = rownorm(out + x); fragment sum/count via atomics
__global__ __launch_bounds__(256) void k_nodef(cfp out, cfp x, cip n2f, fpt fragsum, fpt fragcnt){
    int n = blockIdx.x*256 + threadIdx.x;
    if(n>=NN) return;
    float v[H]; float ss=0.f;
    const float4* op=(const float4*)(out + (size_t)n*H);
    const float4* xp=(const float4*)(x + (size_t)n*H);
    #pragma unroll
    for(int i=0;i<11;i++){
        float4 a=op[i], b=xp[i];
        v[4*i]=a.x+b.x; v[4*i+1]=a.y+b.y; v[4*i+2]=a.z+b.z; v[4*i+3]=a.w+b.w;
    }
    #pragma unroll
    for(int o=0;o<H;o++) ss+=v[o]*v[o];
    float inv = 1.f/fmaxf(sqrtf(ss),1e-12f);
    int f = n2f[n];
    float* fs = fragsum + (size_t)f*H;
    #pragma unroll
    for(int o=0;o<H;o++) atomicAdd(fs+o, v[o]*inv);
    atomicAdd(fragcnt+f, 1.f);
}

// frag = fragsum/cnt; z = frag@Wc1+bc1; column stats (shuffle-reduced); graph sum/sq/cnt
__global__ __launch_bounds__(256) void k_fragz(cfp fragsum, cfp fragcnt, cfp Wc1, cfp bc1, cip f2g,
                                               fpt frag, fpt z, fpt colstat, fpt gsum, fpt gsq, fpt gcnt){
    __shared__ float sW[HH];
    __shared__ float sb[H];
    for(int i=threadIdx.x;i<HH;i+=256) sW[i]=Wc1[i];
    if(threadIdx.x<H) sb[threadIdx.x]=bc1[threadIdx.x];
    __syncthreads();
    int f = blockIdx.x*256 + threadIdx.x;
    bool valid = f < NFRAG;
    int fc = valid ? f : NFRAG-1;
    float inv = valid ? 1.f/fmaxf(fragcnt[fc],1.f) : 0.f;
    float fr[H];
    #pragma unroll
    for(int o=0;o<H;o++) fr[o]=fragsum[(size_t)fc*H+o]*inv;
    float zr[H];
    #pragma unroll
    for(int o=0;o<H;o++) zr[o]=sb[o];
    for(int h=0;h<H;h++){
        float fh = fragsum[(size_t)fc*H+h]*inv;
        const float4* wr=(const float4*)(sW + h*H);
        #pragma unroll
        for(int o=0;o<11;o++){
            float4 w=wr[o];
            zr[4*o]+=fh*w.x; zr[4*o+1]+=fh*w.y; zr[4*o+2]+=fh*w.z; zr[4*o+3]+=fh*w.w;
        }
    }
    if(valid){
        float4* fw=(float4*)(frag+(size_t)f*H);
        float4* zw=(float4*)(z+(size_t)f*H);
        #pragma unroll
        for(int i=0;i<11;i++){
            fw[i]=make_float4(fr[4*i],fr[4*i+1],fr[4*i+2],fr[4*i+3]);
            zw[i]=make_float4(zr[4*i],zr[4*i+1],zr[4*i+2],zr[4*i+3]);
        }
        int g = f2g[f];
        float* gs=gsum+(size_t)g*H; float* gq=gsq+(size_t)g*H;
        #pragma unroll
        for(int o=0;o<H;o++){ atomicAdd(gs+o,fr[o]); atomicAdd(gq+o,fr[o]*fr[o]); }
        atomicAdd(gcnt+g,1.f);
    }
    // column sums for batchnorm: wave-reduce then one atomic per wave
    #pragma unroll
    for(int o=0;o<H;o++){
        float s = valid ? zr[o] : 0.f;
        float q = s*s;
        #pragma unroll
        for(int dlt=32;dlt>0;dlt>>=1){ s+=__shfl_xor(s,dlt); q+=__shfl_xor(q,dlt); }
        if((threadIdx.x&63)==0){ atomicAdd(colstat+o,s); atomicAdd(colstat+H+o,q); }
    }
}

__global__ void k_gstats(cfp gsum, cfp gsq, cfp gcnt, fpt gmean, fpt gstd){
    int i = blockIdx.x*256 + threadIdx.x;
    if(i>=NGRAPH*H) return;
    int g = i / H;
    float c = gcnt[g];
    float mean = gsum[i]/fmaxf(c,1.f);
    float var = (gsq[i] - c*mean*mean)/fmaxf(c-1.f,1.f);
    gmean[i]=mean;
    gstd[i]=sqrtf(fmaxf(var,0.f));
}

// batchnorm + classifier head: w = sigmoid(relu(bn(z)) @ Wc2 + bc2); preserve count
__global__ __launch_bounds__(256) void k_bnw(cfp z, cfp colstat, cfp bng, cfp bnb, cfp Wc2, cfp bc2, fpt w, fpt pres){
    int f = blockIdx.x*256 + threadIdx.x;
    bool valid = f < NFRAG;
    int fc = valid ? f : NFRAG-1;
    float s = 0.f;
    #pragma unroll
    for(int o=0;o<H;o++){
        float mean = colstat[o]*(1.f/NFRAG);
        float var  = colstat[H+o]*(1.f/NFRAG) - mean*mean;
        float zb = (z[(size_t)fc*H+o]-mean)*rsqrtf(var+1e-5f)*bng[o]+bnb[o];
        s += relu_(zb)*Wc2[o];
    }
    float wv = sigmoid_(s + bc2[0]);
    if(valid) w[f]=wv;
    unsigned long long msk = __ballot(valid && (wv > 0.5f));
    if((threadIdx.x&63)==0) atomicAdd(pres,(float)__popcll(msk));
}

// noisy aggregation + KL terms
__global__ __launch_bounds__(256) void k_noisy(cfp frag, cfp w, cfp gmean, cfp gstd, cfp noise, cip f2g,
                                               fpt subsum, fpt kl1, fpt kl2){
    int f = blockIdx.x*256 + threadIdx.x;
    if(f>=NFRAG) return;
    int g = f2g[f];
    float lp = w[f], ln = 1.f-lp;
    float a1 = 0.f;
    float* sb = subsum+(size_t)g*H;
    float* k2 = kl2+(size_t)g*H;
    #pragma unroll
    for(int o=0;o<H;o++){
        float fr = frag[(size_t)f*H+o];
        float mf = gmean[(size_t)g*H+o];
        float sf = gstd[(size_t)g*H+o];
        float nm = lp*fr + ln*mf;
        float ns = ln*sf;
        float ny = nm + noise[(size_t)f*H+o]*ns;
        atomicAdd(sb+o, ny);
        float se = sf + 1e-7f;
        float dd = (nm-mf)/se;
        atomicAdd(k2+o, dd*dd);
        float r = ns/se;
        a1 += r*r;
    }
    atomicAdd(kl1+g, 0.5f*a1*(1.f/(float)H));
}

// per-graph MLP head -> pred
__global__ __launch_bounds__(256) void k_pred(cfp subsum, cfp gcnt, cfp Wp1, cfp bp1, cfp Wp2, cfp bp2,
                                              cfp Wp3, cfp bp3, fpt outp){
    __shared__ float ssub[H];
    __shared__ float sh1[256];
    __shared__ float sh2[128];
    int g = blockIdx.x; int tid = threadIdx.x;
    if(tid<H) ssub[tid] = subsum[(size_t)g*H+tid]/fmaxf(gcnt[g],1.f);
    __syncthreads();
    float a = bp1[tid];
    for(int o=0;o<H;o++) a += ssub[o]*Wp1[(size_t)o*256+tid];
    sh1[tid]=relu_(a);
    __syncthreads();
    if(tid<128){
        float b = bp2[tid];
        for(int i=0;i<256;i++) b += sh1[i]*Wp2[(size_t)i*128+tid];
        sh2[tid]=relu_(b);
    }
    __syncthreads();
    if(tid<64){
        float s = sh2[tid]*Wp3[tid] + sh2[tid+64]*Wp3[tid+64];
        #pragma unroll
        for(int dlt=32;dlt>0;dlt>>=1) s+=__shfl_xor(s,dlt);
        if(tid==0) outp[g]=sigmoid_(s+bp3[0]);
    }
}

// kl.mean + preserve_rate
__global__ void k_final(cfp kl1, cfp kl2, cfp pres, fpt outp){
    float s = 0.f;
    for(int i=threadIdx.x;i<NGRAPH*H;i+=256) s+=kl2[i];
    for(int i=threadIdx.x;i<NGRAPH;i+=256) s+=(float)H*kl1[i];
    __shared__ float red[4];
    #pragma unroll
    for(int dlt=32;dlt>0;dlt>>=1) s+=__shfl_xor(s,dlt);
    int wid = threadIdx.x>>6;
    if((threadIdx.x&63)==0) red[wid]=s;
    __syncthreads();
    if(threadIdx.x==0){
        float tot = red[0]+red[1]+red[2]+red[3];
        outp[NGRAPH]   = tot/(float)(NGRAPH*H);
        outp[NGRAPH+1] = pres[0]/(float)NFRAG;
    }
}

extern "C" void kernel_launch(void* const* d_in, const int* in_sizes, int n_in,
                              void* d_out, int out_size, void* d_ws, size_t ws_size,
                              hipStream_t stream) {
    (void)in_sizes; (void)n_in; (void)out_size; (void)ws_size;
    const float* x        =(const float*)d_in[0];
    const float* edge_attr=(const float*)d_in[1];
    const float* noise    =(const float*)d_in[2];
    const float* W0       =(const float*)d_in[3];
    const float* b0       =(const float*)d_in[4];
    const float* We1      =(const float*)d_in[5];
    const float* be1      =(const float*)d_in[6];
    const float* We2      =(const float*)d_in[7];
    const float* be2      =(const float*)d_in[8];
    const float* root     =(const float*)d_in[9];
    const float* conv_b   =(const float*)d_in[10];
    const float* Wm       =(const float*)d_in[11];
    const float* bm       =(const float*)d_in[12];
    const float* Wc1      =(const float*)d_in[13];
    const float* bc1      =(const float*)d_in[14];
    const float* bng      =(const float*)d_in[15];
    const float* bnb      =(const float*)d_in[16];
    const float* Wc2      =(const float*)d_in[17];
    const float* bc2      =(const float*)d_in[18];
    const float* Wp1      =(const float*)d_in[19];
    const float* bp1      =(const float*)d_in[20];
    const float* Wp2      =(const float*)d_in[21];
    const float* bp2      =(const float*)d_in[22];
    const float* Wp3      =(const float*)d_in[23];
    const float* bp3      =(const float*)d_in[24];
    const int*   ei       =(const int*)d_in[25];
    const int*   n2f      =(const int*)d_in[26];
    const int*   f2g      =(const int*)d_in[27];

    float* ws = (float*)d_ws;
    const size_t NH = (size_t)NN*H;
    float* out_a  = ws;
    float* out_b  = out_a + NH;
    float* b2_a   = out_b + NH;
    float* b2_b   = b2_a + NH;
    float* agg    = b2_b + NH;
    float* tbuf   = agg + NH;
    float* zero0  = tbuf + (size_t)NE*EDIM;
    float* fragsum= zero0;
    float* fragcnt= fragsum + (size_t)NFRAG*H;
    float* colstat= fragcnt + NFRAG;
    float* gsum   = colstat + 2*H;
    float* gsq    = gsum + NGRAPH*H;
    float* gcnt   = gsq + NGRAPH*H;
    float* subsum = gcnt + NGRAPH;
    float* kl1    = subsum + NGRAPH*H;
    float* kl2    = kl1 + NGRAPH;
    float* pres   = kl2 + NGRAPH*H;
    float* zend   = pres + 4;
    float* frag   = zend;
    float* zbuf   = frag + (size_t)NFRAG*H;
    float* wv     = zbuf + (size_t)NFRAG*H;
    float* gmean  = wv + NFRAG;
    float* gstd   = gmean + NGRAPH*H;

    size_t zero_len = (size_t)(zend - zero0);
    hipMemsetAsync(zero0, 0, zero_len*sizeof(float), stream);

    const int nb_n = (NN + 255)/256;
    const int nb_e = (NE + 255)/256;
    const int nb_f = (NFRAG + 255)/256;

    k_in  <<<nb_n,256,0,stream>>>(x, W0, b0, out_a);
    k_b2  <<<nb_n,256,0,stream>>>(out_a, be2, b2_a);
    k_edge<<<nb_e,256,0,stream>>>(edge_attr, We1, be1, tbuf);

    float* cur = out_a; float* curb = b2_a;
    float* nxt = out_b; float* nxtb = b2_b;
    for(int it=0; it<3; ++it){
        hipMemsetAsync(agg, 0, NH*sizeof(float), stream);
        k_msg <<<nb_e,256,0,stream>>>(cur, curb, tbuf, We2, ei, agg);
        k_comb<<<nb_n,256,0,stream>>>(cur, agg, root, conv_b, Wm, bm, nxt);
        if(it<2) k_b2<<<nb_n,256,0,stream>>>(nxt, be2, nxtb);
        float* tp;
        tp=cur; cur=nxt; nxt=tp;
        tp=curb; curb=nxtb; nxtb=tp;
    }

    k_nodef<<<nb_n,256,0,stream>>>(cur, x, n2f, fragsum, fragcnt);
    k_fragz<<<nb_f,256,0,stream>>>(fragsum, fragcnt, Wc1, bc1, f2g, frag, zbuf, colstat, gsum, gsq, gcnt);
    k_gstats<<<(NGRAPH*H+255)/256,256,0,stream>>>(gsum, gsq, gcnt, gmean, gstd);
    k_bnw <<<nb_f,256,0,stream>>>(zbuf, colstat, bng, bnb, Wc2, bc2, wv, pres);
    k_noisy<<<nb_f,256,0,stream>>>(frag, wv, gmean, gstd, noise, f2g, subsum, kl1, kl2);
    k_pred<<<NGRAPH,256,0,stream>>>(subsum, gcnt, Wp1, bp1, Wp2, bp2, Wp3, bp3, (float*)d_out);
    k_final<<<1,256,0,stream>>>(kl1, kl2, pres, (float*)d_out);
}

// Round 2
// 1409.571 us; speedup vs baseline: 1.6518x; 1.6518x over previous
//
#include <hip/hip_runtime.h>
#include <math.h>

#define NN 75000
#define NE 150000
#define H 44
#define HH 1936          // H*H
#define EDIM 10
#define NFRAG 15000
#define NGRAPH 1500

typedef const float* __restrict__ cfp;
typedef float* __restrict__ fpt;
typedef const int* __restrict__ cip;
typedef int* __restrict__ ipt;

__device__ __forceinline__ float relu_(float v){ return v > 0.f ? v : 0.f; }
__device__ __forceinline__ float sigmoid_(float v){ return 1.f/(1.f + expf(-v)); }

// ---------------- CSR build (dst-major) ----------------
__global__ __launch_bounds__(256) void k_hist(cip ei, ipt cnt){
    int e = blockIdx.x*256 + threadIdx.x;
    if(e>=NE) return;
    atomicAdd(&cnt[ei[NE+e]], 1);
}

__global__ __launch_bounds__(1024) void k_scan1(cip cnt, ipt incl, ipt bsum){
    __shared__ int sd[1024];
    int i = blockIdx.x*1024 + threadIdx.x;
    int v = (i<NN)? cnt[i] : 0;
    sd[threadIdx.x]=v;
    __syncthreads();
    for(int off=1; off<1024; off<<=1){
        int t = (threadIdx.x>=off)? sd[threadIdx.x-off] : 0;
        __syncthreads();
        sd[threadIdx.x]+=t;
        __syncthreads();
    }
    if(i<NN) incl[i]=sd[threadIdx.x];
    if(threadIdx.x==1023) bsum[blockIdx.x]=sd[1023];
}

__global__ void k_scan2(ipt bsum, int nblk){
    if(threadIdx.x==0 && blockIdx.x==0){
        int run=0;
        for(int b=0;b<nblk;b++){ int t=bsum[b]; bsum[b]=run; run+=t; }
    }
}

__global__ __launch_bounds__(1024) void k_scan3(cip incl, cip bsum, ipt rowptr){
    int i = blockIdx.x*1024 + threadIdx.x;
    if(i==0) rowptr[0]=0;
    if(i<NN) rowptr[i+1] = incl[i] + bsum[i>>10];
}

__global__ __launch_bounds__(256) void k_scatter(cip ei, cip rowptr, ipt cur, ipt eidx){
    int e = blockIdx.x*256 + threadIdx.x;
    if(e>=NE) return;
    int d = ei[NE+e];
    int pos = rowptr[d] + atomicAdd(&cur[d],1);
    eidx[pos]=e;
}

// ---------------- out = relu(x @ W0 + b0) ----------------
__global__ __launch_bounds__(256) void k_in(cfp x, cfp W0, cfp b0, fpt out){
    __shared__ float sW[HH];
    __shared__ float sb[H];
    for(int i=threadIdx.x;i<HH;i+=256) sW[i]=W0[i];
    if(threadIdx.x<H) sb[threadIdx.x]=b0[threadIdx.x];
    __syncthreads();
    int n = blockIdx.x*256 + threadIdx.x;
    if(n>=NN) return;
    float xv[H];
    const float4* xp = (const float4*)(x + (size_t)n*H);
    #pragma unroll
    for(int i=0;i<11;i++){ float4 v=xp[i]; xv[4*i]=v.x; xv[4*i+1]=v.y; xv[4*i+2]=v.z; xv[4*i+3]=v.w; }
    float acc[H];
    #pragma unroll
    for(int o=0;o<H;o++) acc[o]=sb[o];
    #pragma unroll
    for(int h=0;h<H;h++){
        float xh = xv[h];
        const float4* wr = (const float4*)(sW + h*H);
        #pragma unroll
        for(int o=0;o<11;o++){
            float4 w = wr[o];
            acc[4*o]+=xh*w.x; acc[4*o+1]+=xh*w.y; acc[4*o+2]+=xh*w.z; acc[4*o+3]+=xh*w.w;
        }
    }
    float4* op = (float4*)(out + (size_t)n*H);
    #pragma unroll
    for(int i=0;i<11;i++) op[i] = make_float4(relu_(acc[4*i]),relu_(acc[4*i+1]),relu_(acc[4*i+2]),relu_(acc[4*i+3]));
}

// ---------------- b2[n,o] = sum_h out[n,h] * be2[h*H+o] ----------------
__global__ __launch_bounds__(256) void k_b2(cfp out, cfp be2, fpt b2){
    __shared__ float sB[HH];
    for(int i=threadIdx.x;i<HH;i+=256) sB[i]=be2[i];
    __syncthreads();
    int n = blockIdx.x*256 + threadIdx.x;
    if(n>=NN) return;
    float ov[H];
    const float4* op = (const float4*)(out + (size_t)n*H);
    #pragma unroll
    for(int i=0;i<11;i++){ float4 v=op[i]; ov[4*i]=v.x; ov[4*i+1]=v.y; ov[4*i+2]=v.z; ov[4*i+3]=v.w; }
    float acc[H];
    #pragma unroll
    for(int o=0;o<H;o++) acc[o]=0.f;
    #pragma unroll
    for(int h=0;h<H;h++){
        float oh = ov[h];
        const float4* wr = (const float4*)(sB + h*H);
        #pragma unroll
        for(int o=0;o<11;o++){
            float4 w = wr[o];
            acc[4*o]+=oh*w.x; acc[4*o+1]+=oh*w.y; acc[4*o+2]+=oh*w.z; acc[4*o+3]+=oh*w.w;
        }
    }
    float4* bp = (float4*)(b2 + (size_t)n*H);
    #pragma unroll
    for(int i=0;i<11;i++) bp[i] = make_float4(acc[4*i],acc[4*i+1],acc[4*i+2],acc[4*i+3]);
}

// ---------------- t = relu(edge_attr @ We1 + be1) ----------------
__global__ __launch_bounds__(256) void k_edge(cfp ea, cfp We1, cfp be1, fpt t){
    __shared__ float sW[EDIM*EDIM];
    __shared__ float sb[EDIM];
    if(threadIdx.x<EDIM*EDIM) sW[threadIdx.x]=We1[threadIdx.x];
    if(threadIdx.x<EDIM) sb[threadIdx.x]=be1[threadIdx.x];
    __syncthreads();
    int e = blockIdx.x*256 + threadIdx.x;
    if(e>=NE) return;
    float acc[EDIM];
    #pragma unroll
    for(int j=0;j<EDIM;j++) acc[j]=sb[j];
    #pragma unroll
    for(int k=0;k<EDIM;k++){
        float a = ea[(size_t)e*EDIM + k];
        #pragma unroll
        for(int j=0;j<EDIM;j++) acc[j]+=a*sW[k*EDIM+j];
    }
    #pragma unroll
    for(int j=0;j<EDIM;j++) t[(size_t)e*EDIM+j]=relu_(acc[j]);
}

// ---------------- per-edge message, 2 edges/thread, no atomics ----------------
// msg[e,o] = sum_k sum_h t[e,k]*out[src,h]*We2[k,h*H+o] + b2[src,o]
__global__ __launch_bounds__(256,2) void k_msg2(cfp out, cfp b2, cfp t, cfp We2, cip ei, fpt msgbuf){
    __shared__ float4 sW[EDIM*HH/4];   // 77440 B
    const float4* wg = (const float4*)We2;
    for(int i=threadIdx.x;i<EDIM*HH/4;i+=256) sW[i]=wg[i];
    __syncthreads();
    int e0 = blockIdx.x*256 + threadIdx.x;
    if(e0 >= NE/2) return;
    int e1 = e0 + NE/2;
    int s0 = ei[e0], s1 = ei[e1];
    float ov0[H], ov1[H];
    const float4* p0 = (const float4*)(out + (size_t)s0*H);
    const float4* p1 = (const float4*)(out + (size_t)s1*H);
    #pragma unroll
    for(int i=0;i<11;i++){
        float4 a=p0[i]; ov0[4*i]=a.x; ov0[4*i+1]=a.y; ov0[4*i+2]=a.z; ov0[4*i+3]=a.w;
        float4 b=p1[i]; ov1[4*i]=b.x; ov1[4*i+1]=b.y; ov1[4*i+2]=b.z; ov1[4*i+3]=b.w;
    }
    float4 m0[11], m1[11];
    const float4* q0 = (const float4*)(b2 + (size_t)s0*H);
    const float4* q1 = (const float4*)(b2 + (size_t)s1*H);
    #pragma unroll
    for(int i=0;i<11;i++){ m0[i]=q0[i]; m1[i]=q1[i]; }
    for(int k=0;k<EDIM;k++){
        float t0 = t[(size_t)e0*EDIM + k];
        float t1 = t[(size_t)e1*EDIM + k];
        const float4* wrow = &sW[k*(HH/4)];
        #pragma unroll
        for(int h=0;h<H;h++){
            float z0 = t0*ov0[h];
            float z1 = t1*ov1[h];
            #pragma unroll
            for(int o=0;o<11;o++){
                float4 w = wrow[h*11+o];
                m0[o].x+=z0*w.x; m0[o].y+=z0*w.y; m0[o].z+=z0*w.z; m0[o].w+=z0*w.w;
                m1[o].x+=z1*w.x; m1[o].y+=z1*w.y; m1[o].z+=z1*w.z; m1[o].w+=z1*w.w;
            }
        }
    }
    float4* w0 = (float4*)(msgbuf + (size_t)e0*H);
    float4* w1 = (float4*)(msgbuf + (size_t)e1*H);
    #pragma unroll
    for(int o=0;o<11;o++){ w0[o]=m0[o]; w1[o]=m1[o]; }
}

// ---------------- gather + combine: m=relu(sum msg + out@root + cb); out'=[m,out]@Wm+bm ----------------
__global__ __launch_bounds__(256,2) void k_comb(cfp out, cfp msgbuf, cip rowptr, cip eidx,
                                                cfp root, cfp conv_b, cfp Wm, cfp bm, fpt out_nxt){
    __shared__ float sR[HH];
    __shared__ float sM[2*HH];
    __shared__ float scb[H];
    __shared__ float sbm[H];
    for(int i=threadIdx.x;i<HH;i+=256) sR[i]=root[i];
    for(int i=threadIdx.x;i<2*HH;i+=256) sM[i]=Wm[i];
    if(threadIdx.x<H){ scb[threadIdx.x]=conv_b[threadIdx.x]; sbm[threadIdx.x]=bm[threadIdx.x]; }
    __syncthreads();
    int n = blockIdx.x*256 + threadIdx.x;
    if(n>=NN) return;
    float m[H];
    #pragma unroll
    for(int o=0;o<H;o++) m[o]=scb[o];
    // gather in-edge messages (CSR)
    int st = rowptr[n], en = rowptr[n+1];
    for(int j=st;j<en;j++){
        int e = eidx[j];
        const float4* mp = (const float4*)(msgbuf + (size_t)e*H);
        #pragma unroll
        for(int i=0;i<11;i++){
            float4 v=mp[i];
            m[4*i]+=v.x; m[4*i+1]+=v.y; m[4*i+2]+=v.z; m[4*i+3]+=v.w;
        }
    }
    float ov[H];
    const float4* op = (const float4*)(out + (size_t)n*H);
    #pragma unroll
    for(int i=0;i<11;i++){ float4 v=op[i]; ov[4*i]=v.x; ov[4*i+1]=v.y; ov[4*i+2]=v.z; ov[4*i+3]=v.w; }
    #pragma unroll
    for(int h=0;h<H;h++){
        float oh = ov[h];
        const float4* wr = (const float4*)(sR + h*H);
        #pragma unroll
        for(int o=0;o<11;o++){
            float4 w=wr[o];
            m[4*o]+=oh*w.x; m[4*o+1]+=oh*w.y; m[4*o+2]+=oh*w.z; m[4*o+3]+=oh*w.w;
        }
    }
    #pragma unroll
    for(int o=0;o<H;o++) m[o]=relu_(m[o]);
    float no[H];
    #pragma unroll
    for(int o=0;o<H;o++) no[o]=sbm[o];
    #pragma unroll
    for(int h=0;h<H;h++){
        float mh = m[h];
        float oh = ov[h];
        const float4* w1 = (const float4*)(sM + h*H);
        const float4* w2 = (const float4*)(sM + (H+h)*H);
        #pragma unroll
        for(int o=0;o<11;o++){
            float4 a=w1[o], b=w2[o];
            no[4*o]+=mh*a.x+oh*b.x; no[4*o+1]+=mh*a.y+oh*b.y; no[4*o+2]+=mh*a.z+oh*b.z; no[4*o+3]+=mh*a.w+oh*b.w;
        }
    }
    float4* np_ = (float4*)(out_nxt + (size_t)n*H);
    #pragma unroll
    for(int i=0;i<11;i++) np_[i]=make_float4(no[4*i],no[4*i+1],no[4*i+2],no[4*i+3]);
}

// ---------------- fragment stage: thread per frag (nodes 5f..5f+4), no atomics except colstat ----------------
__global__ __launch_bounds__(256) void k_frag(cfp out, cfp x, cfp Wc1, cfp bc1,
                                              fpt frag, fpt z, fpt colstat){
    __shared__ float sW[HH];
    __shared__ float sb[H];
    for(int i=threadIdx.x;i<HH;i+=256) sW[i]=Wc1[i];
    if(threadIdx.x<H) sb[threadIdx.x]=bc1[threadIdx.x];
    __syncthreads();
    int f = blockIdx.x*256 + threadIdx.x;
    bool valid = f < NFRAG;
    int fc = valid ? f : NFRAG-1;
    float fr[H];
    #pragma unroll
    for(int o=0;o<H;o++) fr[o]=0.f;
    for(int j=0;j<5;j++){
        int n = 5*fc + j;
        float v[H]; float ss=0.f;
        const float4* op=(const float4*)(out + (size_t)n*H);
        const float4* xp=(const float4*)(x + (size_t)n*H);
        #pragma unroll
        for(int i=0;i<11;i++){
            float4 a=op[i], b=xp[i];
            v[4*i]=a.x+b.x; v[4*i+1]=a.y+b.y; v[4*i+2]=a.z+b.z; v[4*i+3]=a.w+b.w;
        }
        #pragma unroll
        for(int o=0;o<H;o++) ss+=v[o]*v[o];
        float inv = 1.f/fmaxf(sqrtf(ss),1e-12f);
        #pragma unroll
        for(int o=0;o<H;o++) fr[o]+=v[o]*inv;
    }
    #pragma unroll
    for(int o=0;o<H;o++) fr[o]*=0.2f;     // mean of exactly 5 nodes per fragment
    float zr[H];
    #pragma unroll
    for(int o=0;o<H;o++) zr[o]=sb[o];
    #pragma unroll
    for(int h=0;h<H;h++){
        float fh = fr[h];
        const float4* wr=(const float4*)(sW + h*H);
        #pragma unroll
        for(int o=0;o<11;o++){
            float4 w=wr[o];
            zr[4*o]+=fh*w.x; zr[4*o+1]+=fh*w.y; zr[4*o+2]+=fh*w.z; zr[4*o+3]+=fh*w.w;
        }
    }
    if(valid){
        float4* fw=(float4*)(frag+(size_t)f*H);
        float4* zw=(float4*)(z+(size_t)f*H);
        #pragma unroll
        for(int i=0;i<11;i++){
            fw[i]=make_float4(fr[4*i],fr[4*i+1],fr[4*i+2],fr[4*i+3]);
            zw[i]=make_float4(zr[4*i],zr[4*i+1],zr[4*i+2],zr[4*i+3]);
        }
    }
    // column sums for batchnorm: wave-reduce then one atomic per wave per column
    #pragma unroll
    for(int o=0;o<H;o++){
        float s = valid ? zr[o] : 0.f;
        float q = s*s;
        #pragma unroll
        for(int dlt=32;dlt>0;dlt>>=1){ s+=__shfl_xor(s,dlt); q+=__shfl_xor(q,dlt); }
        if((threadIdx.x&63)==0){ atomicAdd(colstat+o,s); atomicAdd(colstat+H+o,q); }
    }
}

// ---------------- batchnorm + classifier: w = sigmoid(relu(bn(z)) @ Wc2 + bc2) ----------------
__global__ __launch_bounds__(256) void k_bnw(cfp z, cfp colstat, cfp bng, cfp bnb, cfp Wc2, cfp bc2, fpt w, fpt pres){
    int f = blockIdx.x*256 + threadIdx.x;
    bool valid = f < NFRAG;
    int fc = valid ? f : NFRAG-1;
    float s = 0.f;
    #pragma unroll
    for(int o=0;o<H;o++){
        float mean = colstat[o]*(1.f/NFRAG);
        float var  = colstat[H+o]*(1.f/NFRAG) - mean*mean;
        float zb = (z[(size_t)fc*H+o]-mean)*rsqrtf(var+1e-5f)*bng[o]+bnb[o];
        s += relu_(zb)*Wc2[o];
    }
    float wv = sigmoid_(s + bc2[0]);
    if(valid) w[f]=wv;
    unsigned long long msk = __ballot(valid && (wv > 0.5f));
    if((threadIdx.x&63)==0) atomicAdd(pres,(float)__popcll(msk));
}

// ---------------- per-graph: gmean/gstd + noisy + KL, one wave per graph (frags 10g..10g+9) ----------------
__global__ __launch_bounds__(64) void k_graph(cfp frag, cfp w, cfp noise, fpt sub, fpt klg){
    int g = blockIdx.x;
    int o = threadIdx.x;
    bool act = o < H;
    int oc = act ? o : 0;
    float frv[10];
    #pragma unroll
    for(int j=0;j<10;j++) frv[j] = act ? frag[(size_t)(10*g+j)*H + oc] : 0.f;
    float gs=0.f, gq=0.f;
    #pragma unroll
    for(int j=0;j<10;j++){ gs+=frv[j]; gq+=frv[j]*frv[j]; }
    float gmean = gs*0.1f;
    float gvar  = (gq - 10.f*gmean*gmean)*(1.f/9.f);
    float gstd  = sqrtf(fmaxf(gvar,0.f));
    float se    = gstd + 1e-7f;
    float c     = act ? (gstd/se)*(gstd/se) : 0.f;
    float C = c;
    #pragma unroll
    for(int dlt=32;dlt>0;dlt>>=1) C+=__shfl_xor(C,dlt);
    float subacc=0.f, B=0.f, Sln=0.f;
    #pragma unroll
    for(int j=0;j<10;j++){
        float lp = w[10*g+j];
        float ln = 1.f-lp;
        Sln += ln*ln;
        float nm = lp*frv[j] + ln*gmean;
        float ns = ln*gstd;
        float ny = nm + (act ? noise[(size_t)(10*g+j)*H + oc] : 0.f)*ns;
        subacc += ny;
        float dd = (nm-gmean)/se;
        B += dd*dd;
    }
    if(act) sub[(size_t)g*H+o] = subacc*0.1f;   // mean of exactly 10 frags
    float Bv = act ? B : 0.f;
    #pragma unroll
    for(int dlt=32;dlt>0;dlt>>=1) Bv+=__shfl_xor(Bv,dlt);
    if(o==0) klg[g] = 0.5f*C*Sln + Bv;
}

// ---------------- per-graph MLP head -> pred ----------------
__global__ __launch_bounds__(256) void k_pred(cfp sub, cfp Wp1, cfp bp1, cfp Wp2, cfp bp2,
                                              cfp Wp3, cfp bp3, fpt outp){
    __shared__ float ssub[H];
    __shared__ float sh1[256];
    __shared__ float sh2[128];
    int g = blockIdx.x; int tid = threadIdx.x;
    if(tid<H) ssub[tid] = sub[(size_t)g*H+tid];
    __syncthreads();
    float a = bp1[tid];
    for(int o=0;o<H;o++) a += ssub[o]*Wp1[(size_t)o*256+tid];
    sh1[tid]=relu_(a);
    __syncthreads();
    if(tid<128){
        float b = bp2[tid];
        for(int i=0;i<256;i++) b += sh1[i]*Wp2[(size_t)i*128+tid];
        sh2[tid]=relu_(b);
    }
    __syncthreads();
    if(tid<64){
        float s = sh2[tid]*Wp3[tid] + sh2[tid+64]*Wp3[tid+64];
        #pragma unroll
        for(int dlt=32;dlt>0;dlt>>=1) s+=__shfl_xor(s,dlt);
        if(tid==0) outp[g]=sigmoid_(s+bp3[0]);
    }
}

// ---------------- kl.mean + preserve_rate ----------------
__global__ void k_final(cfp klg, cfp pres, fpt outp){
    float s = 0.f;
    for(int i=threadIdx.x;i<NGRAPH;i+=256) s+=klg[i];
    __shared__ float red[4];
    #pragma unroll
    for(int dlt=32;dlt>0;dlt>>=1) s+=__shfl_xor(s,dlt);
    int wid = threadIdx.x>>6;
    if((threadIdx.x&63)==0) red[wid]=s;
    __syncthreads();
    if(threadIdx.x==0){
        float tot = red[0]+red[1]+red[2]+red[3];
        outp[NGRAPH]   = tot/(float)(NGRAPH*H);
        outp[NGRAPH+1] = pres[0]/(float)NFRAG;
    }
}

extern "C" void kernel_launch(void* const* d_in, const int* in_sizes, int n_in,
                              void* d_out, int out_size, void* d_ws, size_t ws_size,
                              hipStream_t stream) {
    (void)in_sizes; (void)n_in; (void)out_size; (void)ws_size;
    const float* x        =(const float*)d_in[0];
    const float* edge_attr=(const float*)d_in[1];
    const float* noise    =(const float*)d_in[2];
    const float* W0       =(const float*)d_in[3];
    const float* b0       =(const float*)d_in[4];
    const float* We1      =(const float*)d_in[5];
    const float* be1      =(const float*)d_in[6];
    const float* We2      =(const float*)d_in[7];
    const float* be2      =(const float*)d_in[8];
    const float* root     =(const float*)d_in[9];
    const float* conv_b   =(const float*)d_in[10];
    const float* Wm       =(const float*)d_in[11];
    const float* bm       =(const float*)d_in[12];
    const float* Wc1      =(const float*)d_in[13];
    const float* bc1      =(const float*)d_in[14];
    const float* bng      =(const float*)d_in[15];
    const float* bnb      =(const float*)d_in[16];
    const float* Wc2      =(const float*)d_in[17];
    const float* bc2      =(const float*)d_in[18];
    const float* Wp1      =(const float*)d_in[19];
    const float* bp1      =(const float*)d_in[20];
    const float* Wp2      =(const float*)d_in[21];
    const float* bp2      =(const float*)d_in[22];
    const float* Wp3      =(const float*)d_in[23];
    const float* bp3      =(const float*)d_in[24];
    const int*   ei       =(const int*)d_in[25];

    float* ws = (float*)d_ws;
    const size_t NH = (size_t)NN*H;
    float* out_a  = ws;                       // 3.3M
    float* out_b  = out_a + NH;               // 3.3M
    float* b2_a   = out_b + NH;               // 3.3M
    float* b2_b   = b2_a + NH;                // 3.3M
    float* tbuf   = b2_b + NH;                // 1.5M
    float* msgbuf = tbuf + (size_t)NE*EDIM;   // 6.6M
    float* frag   = msgbuf + (size_t)NE*H;    // 0.66M
    float* zbuf   = frag + (size_t)NFRAG*H;   // 0.66M
    float* wv     = zbuf + (size_t)NFRAG*H;   // 15000
    float* sub    = wv + NFRAG;               // 66000
    float* klg    = sub + (size_t)NGRAPH*H;   // 1500
    int*   rowptr = (int*)(klg + NGRAPH);     // 75001
    int*   eidx   = rowptr + (NN+1);          // 150000
    int*   bsum   = eidx + NE;                // 128
    int*   incl   = bsum + 128;               // 75000
    int*   cnt    = incl + NN;                // 75000  (zeroed)
    int*   cur    = cnt + NN;                 // 75000  (zeroed)
    float* colstat= (float*)(cur + NN);       // 88     (zeroed)
    float* pres   = colstat + 2*H;            // 8      (zeroed)

    hipMemsetAsync(cnt, 0, (size_t)(2*NN + 2*H + 8)*sizeof(float), stream);

    const int nb_n = (NN + 255)/256;
    const int nb_e = (NE + 255)/256;
    const int nb_h = (NE/2 + 255)/256;
    const int nb_f = (NFRAG + 255)/256;
    const int nblk = (NN + 1023)/1024;

    // CSR build (once; edges are iteration-invariant)
    k_hist   <<<nb_e,256,0,stream>>>(ei, cnt);
    k_scan1  <<<nblk,1024,0,stream>>>(cnt, incl, bsum);
    k_scan2  <<<1,64,0,stream>>>(bsum, nblk);
    k_scan3  <<<nblk,1024,0,stream>>>(incl, bsum, rowptr);
    k_scatter<<<nb_e,256,0,stream>>>(ei, rowptr, cur, eidx);

    k_in  <<<nb_n,256,0,stream>>>(x, W0, b0, out_a);
    k_b2  <<<nb_n,256,0,stream>>>(out_a, be2, b2_a);
    k_edge<<<nb_e,256,0,stream>>>(edge_attr, We1, be1, tbuf);

    float* cur_o = out_a; float* cur_b = b2_a;
    float* nxt_o = out_b; float* nxt_b = b2_b;
    for(int it=0; it<3; ++it){
        k_msg2<<<nb_h,256,0,stream>>>(cur_o, cur_b, tbuf, We2, ei, msgbuf);
        k_comb<<<nb_n,256,0,stream>>>(cur_o, msgbuf, rowptr, eidx, root, conv_b, Wm, bm, nxt_o);
        if(it<2) k_b2<<<nb_n,256,0,stream>>>(nxt_o, be2, nxt_b);
        float* tp;
        tp=cur_o; cur_o=nxt_o; nxt_o=tp;
        tp=cur_b; cur_b=nxt_b; nxt_b=tp;
    }

    k_frag <<<nb_f,256,0,stream>>>(cur_o, x, Wc1, bc1, frag, zbuf, colstat);
    k_bnw  <<<nb_f,256,0,stream>>>(zbuf, colstat, bng, bnb, Wc2, bc2, wv, pres);
    k_graph<<<NGRAPH,64,0,stream>>>(frag, wv, noise, sub, klg);
    k_pred <<<NGRAPH,256,0,stream>>>(sub, Wp1, bp1, Wp2, bp2, Wp3, bp3, (float*)d_out);
    k_final<<<1,256,0,stream>>>(klg, pres, (float*)d_out);
}